// Round 8
// baseline (72273.218 us; speedup 1.0000x reference)
//
#include <hip/hip_runtime.h>

// ---- layer 0 (scalar f32): gates = [x_t|h0_{t-1}] @ [Wih0|Whh0]^T ----------
// WG (mrow,jblk): 64 batch rows x 8 hidden cols. thread: (b, jj in {jp, jp+4}).
template<bool ENC>
__global__ void __launch_bounds__(256) l0s(
    const float* __restrict__ x, const float* __restrict__ predf,
    const float* __restrict__ Wih, const float* __restrict__ Whh,
    const float* __restrict__ bih, const float* __restrict__ bhh,
    const float* __restrict__ hp, float* __restrict__ hn,
    float* __restrict__ cb, int t)
{
  __shared__ float S[16384];    // 64KB, staged twice
  __shared__ float bs[32];
  const int wg = blockIdx.x, tid = threadIdx.x;
  const int mrow = wg & 3, jblk = wg >> 2;
  const int bl = tid & 63, jp = tid >> 6;
  const int b = mrow*64 + bl;

  // phase 1: Wih slice (32 rows x 64) + bias   (row r = gate*8 + jj)
  for (int i = tid; i < 2048; i += 256){
    int r = i >> 6, k = i & 63;
    int n = (r >> 3)*512 + jblk*8 + (r & 7);
    S[i] = Wih[n*64 + k];
  }
  if (tid < 32){
    int n = (tid >> 3)*512 + jblk*8 + (tid & 7);
    bs[tid] = bih[n] + bhh[n];
  }
  __syncthreads();

  float acc[2][4];
  #pragma unroll
  for (int q = 0; q < 2; ++q)
    #pragma unroll
    for (int gt = 0; gt < 4; ++gt)
      acc[q][gt] = bs[gt*8 + jp + q*4];

  {
    float xv[64];
    if (ENC){
      const float* xb = x + b*21504 + t;        // x[b][d][t], d-stride 336
      #pragma unroll
      for (int k = 0; k < 64; ++k) xv[k] = xb[k*336];
    } else {
      const float* pb = predf + b*64;
      #pragma unroll
      for (int k = 0; k < 64; ++k) xv[k] = pb[k];
    }
    #pragma unroll
    for (int q = 0; q < 2; ++q)
      #pragma unroll
      for (int gt = 0; gt < 4; ++gt){
        const float* wi = S + (gt*8 + jp + q*4)*64;
        float a = acc[q][gt];
        #pragma unroll
        for (int k = 0; k < 64; ++k) a += xv[k]*wi[k];
        acc[q][gt] = a;
      }
  }
  __syncthreads();              // everyone done with phase-1 S

  // phase 2: Whh slice (32 rows x 512)
  for (int i = tid; i < 16384; i += 256){
    int r = i >> 9, k = i & 511;
    int n = (r >> 3)*512 + jblk*8 + (r & 7);
    S[i] = Whh[n*512 + k];
  }
  __syncthreads();

  const float* hb = hp + b*512;
  for (int kb = 0; kb < 8; ++kb){
    float hv[64];
    #pragma unroll
    for (int k = 0; k < 64; ++k) hv[k] = hb[kb*64 + k];
    #pragma unroll
    for (int q = 0; q < 2; ++q)
      #pragma unroll
      for (int gt = 0; gt < 4; ++gt){
        const float* wh = S + (gt*8 + jp + q*4)*512 + kb*64;
        float a = acc[q][gt];
        #pragma unroll
        for (int k = 0; k < 64; ++k) a += hv[k]*wh[k];
        acc[q][gt] = a;
      }
  }

  #pragma unroll
  for (int q = 0; q < 2; ++q){
    float si = 1.f/(1.f + expf(-acc[q][0]));
    float sf = 1.f/(1.f + expf(-acc[q][1]));
    float gg = tanhf(acc[q][2]);
    float so = 1.f/(1.f + expf(-acc[q][3]));
    int gi = b*512 + jblk*8 + jp + q*4;
    float cn = sf*cb[gi] + si*gg;
    cb[gi] = cn;
    hn[gi] = so*tanhf(cn);
  }
}

// ---- layer 1 (scalar f32): gates = [h0_t|h1_{t-1}] @ [Wih1|Whh1]^T ---------
__global__ void __launch_bounds__(256) l1s(
    const float* __restrict__ Wih, const float* __restrict__ Whh,
    const float* __restrict__ bih, const float* __restrict__ bhh,
    const float* __restrict__ h0c, const float* __restrict__ h1p,
    float* __restrict__ h1n, float* __restrict__ cb,
    float* __restrict__ gfout)
{
  __shared__ float S[16384];
  __shared__ float bs[32];
  const int wg = blockIdx.x, tid = threadIdx.x;
  const int mrow = wg & 3, jblk = wg >> 2;
  const int bl = tid & 63, jp = tid >> 6;
  const int b = mrow*64 + bl;

  // phase 1: Wih1 slice (32x512) + bias, accumulate h0-part
  for (int i = tid; i < 16384; i += 256){
    int r = i >> 9, k = i & 511;
    int n = (r >> 3)*512 + jblk*8 + (r & 7);
    S[i] = Wih[n*512 + k];
  }
  if (tid < 32){
    int n = (tid >> 3)*512 + jblk*8 + (tid & 7);
    bs[tid] = bih[n] + bhh[n];
  }
  __syncthreads();

  float acc[2][4];
  #pragma unroll
  for (int q = 0; q < 2; ++q)
    #pragma unroll
    for (int gt = 0; gt < 4; ++gt)
      acc[q][gt] = bs[gt*8 + jp + q*4];

  {
    const float* hb = h0c + b*512;
    for (int kb = 0; kb < 8; ++kb){
      float hv[64];
      #pragma unroll
      for (int k = 0; k < 64; ++k) hv[k] = hb[kb*64 + k];
      #pragma unroll
      for (int q = 0; q < 2; ++q)
        #pragma unroll
        for (int gt = 0; gt < 4; ++gt){
          const float* wh = S + (gt*8 + jp + q*4)*512 + kb*64;
          float a = acc[q][gt];
          #pragma unroll
          for (int k = 0; k < 64; ++k) a += hv[k]*wh[k];
          acc[q][gt] = a;
        }
    }
  }
  __syncthreads();

  // phase 2: Whh1 slice (32x512), accumulate h1-part
  for (int i = tid; i < 16384; i += 256){
    int r = i >> 9, k = i & 511;
    int n = (r >> 3)*512 + jblk*8 + (r & 7);
    S[i] = Whh[n*512 + k];
  }
  __syncthreads();

  {
    const float* hb = h1p + b*512;
    for (int kb = 0; kb < 8; ++kb){
      float hv[64];
      #pragma unroll
      for (int k = 0; k < 64; ++k) hv[k] = hb[kb*64 + k];
      #pragma unroll
      for (int q = 0; q < 2; ++q)
        #pragma unroll
        for (int gt = 0; gt < 4; ++gt){
          const float* wh = S + (gt*8 + jp + q*4)*512 + kb*64;
          float a = acc[q][gt];
          #pragma unroll
          for (int k = 0; k < 64; ++k) a += hv[k]*wh[k];
          acc[q][gt] = a;
        }
    }
  }

  #pragma unroll
  for (int q = 0; q < 2; ++q){
    float si = 1.f/(1.f + expf(-acc[q][0]));
    float sf = 1.f/(1.f + expf(-acc[q][1]));
    float gg = tanhf(acc[q][2]);
    float so = 1.f/(1.f + expf(-acc[q][3]));
    int gi = b*512 + jblk*8 + jp + q*4;
    float cn = sf*cb[gi] + si*gg;
    cb[gi] = cn;
    float h = so*tanhf(cn);
    h1n[gi] = h;
    if (gfout) gfout[gi] = h;     // global_feat (f32!) at last encoder step
  }
}

// ---- decoder: pred = h1_t @ Wout^T + bout (scalar f32) ---------------------
__global__ void __launch_bounds__(256) pred_s(
    const float* __restrict__ h1c, const float* __restrict__ Wout,
    const float* __restrict__ bout, float* __restrict__ predf,
    float* __restrict__ out, int l)
{
  const int wg = blockIdx.x, tid = threadIdx.x;
  const int bsub = tid >> 6, d = tid & 63;
  const int b = wg*4 + bsub;
  float acc = bout[d];
  const float* hr = h1c + b*512;
  const float* wr = Wout + d*512;
  #pragma unroll 8
  for (int k = 0; k < 512; ++k) acc += hr[k]*wr[k];
  predf[b*64 + d] = acc;                            // feedback input (f32)
  out[131072 + (b*64 + d)*96 + l] = acc;            // preds[b][d][l] (f32!)
}

extern "C" void kernel_launch(void* const* d_in, const int* in_sizes, int n_in,
                              void* d_out, int out_size, void* d_ws, size_t ws_size,
                              hipStream_t stream)
{
  const float* x    = (const float*)d_in[0];
  const float* Wih0 = (const float*)d_in[1];
  const float* Whh0 = (const float*)d_in[2];
  const float* bih0 = (const float*)d_in[3];
  const float* bhh0 = (const float*)d_in[4];
  const float* Wih1 = (const float*)d_in[5];
  const float* Whh1 = (const float*)d_in[6];
  const float* bih1 = (const float*)d_in[7];
  const float* bhh1 = (const float*)d_in[8];
  const float* Wout = (const float*)d_in[9];
  const float* bout = (const float*)d_in[10];
  float* out = (float*)d_out;     // f32 output: reference returns float32

  // ws layout (3,211,264 B total, all f32 state)
  char* ws = (char*)d_ws;
  float* h0f[2] = { (float*)(ws + 0),       (float*)(ws + 524288) };
  float* h1f[2] = { (float*)(ws + 1048576), (float*)(ws + 1572864) };
  float* c0     = (float*)(ws + 2097152);
  float* c1     = (float*)(ws + 2621440);
  float* predf  = (float*)(ws + 3145728);

  (void)hipMemsetAsync(d_ws, 0, 3211264, stream);   // zero h/c/pred each call

  for (int t = 0; t < 336; ++t){
    int p = t & 1;
    l0s<true><<<dim3(256), dim3(256), 0, stream>>>(
        x, predf, Wih0, Whh0, bih0, bhh0, h0f[p^1], h0f[p], c0, t);
    l1s<<<dim3(256), dim3(256), 0, stream>>>(
        Wih1, Whh1, bih1, bhh1, h0f[p], h1f[p^1], h1f[p], c1,
        (t == 335) ? out : (float*)nullptr);
  }
  for (int t = 336; t < 432; ++t){
    int p = t & 1;
    l0s<false><<<dim3(256), dim3(256), 0, stream>>>(
        x, predf, Wih0, Whh0, bih0, bhh0, h0f[p^1], h0f[p], c0, t);
    l1s<<<dim3(256), dim3(256), 0, stream>>>(
        Wih1, Whh1, bih1, bhh1, h0f[p], h1f[p^1], h1f[p], c1, (float*)nullptr);
    pred_s<<<dim3(64), dim3(256), 0, stream>>>(
        h1f[p], Wout, bout, predf, out, t - 336);
  }
}

// Round 9
// 23866.350 us; speedup vs baseline: 3.0282x; 3.0282x over previous
//
#include <hip/hip_runtime.h>

typedef unsigned short u16;
typedef __attribute__((ext_vector_type(8))) short short8;
typedef __attribute__((ext_vector_type(4))) float f32x4;

__device__ __forceinline__ float bf2f(u16 v){
  union { unsigned u; float f; } t; t.u = ((unsigned)v) << 16; return t.f;
}
__device__ __forceinline__ u16 f2bf(float f){
  union { float f; unsigned u; } t; t.f = f;
  unsigned u = t.u;
  return (u16)((u + 0x7fffu + ((u >> 16) & 1u)) >> 16);
}
struct HiLo { short hi, lo; };
// RNE hi/lo split of one f32: v ~= hi + lo, |err| ~ 2^-18 |v|
__device__ __forceinline__ HiLo split1(float v){
  HiLo r;
  u16 h = f2bf(v);
  r.hi = (short)h;
  r.lo = (short)f2bf(v - bf2f(h));
  return r;
}
__device__ __forceinline__ void ldw8s(const float* __restrict__ p, short8& hi, short8& lo){
  #pragma unroll
  for (int j = 0; j < 8; ++j){ HiLo s = split1(p[j]); hi[j] = s.hi; lo[j] = s.lo; }
}

#define MFMA(acc, a, b) acc = __builtin_amdgcn_mfma_f32_16x16x32_bf16(a, b, acc, 0,0,0)
// split accumulate: acc += A*B, A=(ah,al), B=(bh,bl), drop lo*lo
#define SMACC(acc, ah, al, bh, bl) do{ MFMA(acc, ah, bh); MFMA(acc, ah, bl); MFMA(acc, al, bh); }while(0)

// ---- weight pre-split: f32 -> (hi,lo) bf16 ---------------------------------
__global__ void wsplit(const float* __restrict__ s, u16* __restrict__ hi,
                       u16* __restrict__ lo, int n){
  int i = blockIdx.x * blockDim.x + threadIdx.x;
  if (i < n){ HiLo r = split1(s[i]); hi[i] = (u16)r.hi; lo[i] = (u16)r.lo; }
}

// B-operand fragment load: pre-split (PS) or in-register split
template<bool PS>
__device__ __forceinline__ void ldB(const float* __restrict__ wf,
                                    const u16* __restrict__ wh,
                                    const u16* __restrict__ wl,
                                    int off, short8& bh, short8& bl_){
  if constexpr (PS){
    bh  = *(const short8*)(wh + off);
    bl_ = *(const short8*)(wl + off);
  } else {
    ldw8s(wf + off, bh, bl_);
  }
}

// Gate exchange + LSTM cell update. WG tile: 64 batch rows x 8 hidden cols.
// LDS gate cols: [0,8)=i [8,16)=f [16,24)=g [24,32)=o. c-state f32 in global.
__device__ __forceinline__ void cell_epilogue(
    float* gl, const float* bs, float* __restrict__ cbuf,
    u16* __restrict__ hhi, u16* __restrict__ hlo,
    float* __restrict__ gfout, int mrow, int jblk,
    const f32x4& a0, const f32x4& a1, int wv, int lane, int tid)
{
  __syncthreads();                      // bias stores visible
  const int rbase = wv*16 + ((lane >> 4) << 2);  // C/D: row=(lane>>4)*4+r, col=lane&15
  const int cI = lane & 15;
  #pragma unroll
  for (int r = 0; r < 4; ++r){
    gl[(rbase+r)*33 + cI]      = a0[r] + bs[cI];
    gl[(rbase+r)*33 + 16 + cI] = a1[r] + bs[16 + cI];
  }
  __syncthreads();
  #pragma unroll
  for (int q = 0; q < 2; ++q){
    int e = tid + q*256;
    int m = e >> 3, jj = e & 7;
    float iv = gl[m*33 + jj];
    float fv = gl[m*33 + 8 + jj];
    float gv = gl[m*33 + 16 + jj];
    float ov = gl[m*33 + 24 + jj];
    float si = 1.f/(1.f + expf(-iv));
    float sf = 1.f/(1.f + expf(-fv));
    float so = 1.f/(1.f + expf(-ov));
    int gi = (mrow*64 + m)*512 + jblk*8 + jj;
    float cn = sf*cbuf[gi] + si*tanhf(gv);
    cbuf[gi] = cn;
    float h = so*tanhf(cn);
    u16 hh = f2bf(h);
    hhi[gi] = hh;
    hlo[gi] = f2bf(h - bf2f(hh));       // residual keeps recurrence ~2^-17
    if (gfout) gfout[gi] = h;           // global_feat (f32) at last encoder step
  }
}

// ---- layer 0: gates = [x_t | h0_{t-1}] @ [Wih0|Whh0]^T ---------------------
template<bool ENC, bool PS>
__global__ void __launch_bounds__(256) l0_step(
    const float* __restrict__ x,
    const u16* __restrict__ predhi, const u16* __restrict__ predlo,
    const float* __restrict__ Wihf, const u16* __restrict__ Wihh, const u16* __restrict__ Wihl,
    const float* __restrict__ Whhf, const u16* __restrict__ Whhh, const u16* __restrict__ Whhl,
    const float* __restrict__ bih, const float* __restrict__ bhh,
    const u16* __restrict__ hphi, const u16* __restrict__ hplo,
    u16* __restrict__ hnhi, u16* __restrict__ hnlo,
    float* __restrict__ c0, int t)
{
  __shared__ float gl[64*33];
  __shared__ float bs[32];
  const int wg = blockIdx.x, tid = threadIdx.x;
  const int mrow = wg & 3, jblk = wg >> 2;
  const int lane = tid & 63, wv = tid >> 6;
  if (tid < 32){
    int n = ((tid >> 3) << 9) + jblk*8 + (tid & 7);
    bs[tid] = bih[n] + bhh[n];
  }
  const int ar = mrow*64 + wv*16 + (lane & 15);   // A row (batch)
  const int kc = (lane >> 4) << 3;                // A/B k offset in 32-step
  const int cI = lane & 15;
  const int n0 = ((cI >> 3) << 9) + jblk*8 + (cI & 7);  // i/f gate rows
  const int n1 = n0 + 1024;                              // g/o gate rows

  f32x4 acc0 = {0,0,0,0}, acc1 = {0,0,0,0};
  #pragma unroll
  for (int ks = 0; ks < 2; ++ks){                 // K seg 0: x/pred (width 64)
    int k = ks*32 + kc;
    short8 ah, al;
    if (ENC){
      const float* xb = x + ar*21504 + t;         // x[b][d][t], d-stride 336
      #pragma unroll
      for (int j = 0; j < 8; ++j){ HiLo s = split1(xb[(k + j)*336]); ah[j] = s.hi; al[j] = s.lo; }
    } else {
      ah = *(const short8*)(predhi + ar*64 + k);
      al = *(const short8*)(predlo + ar*64 + k);
    }
    short8 bh0, bl0, bh1, bl1;
    ldB<PS>(Wihf, Wihh, Wihl, n0*64 + k, bh0, bl0);
    ldB<PS>(Wihf, Wihh, Wihl, n1*64 + k, bh1, bl1);
    SMACC(acc0, ah, al, bh0, bl0);
    SMACC(acc1, ah, al, bh1, bl1);
  }
  const u16* hH = hphi + ar*512 + kc;
  const u16* hL = hplo + ar*512 + kc;
  #pragma unroll 4
  for (int ks = 0; ks < 16; ++ks){                // K seg 1: h0 (width 512)
    int k = ks*32;
    short8 ah = *(const short8*)(hH + k);
    short8 al = *(const short8*)(hL + k);
    short8 bh0, bl0, bh1, bl1;
    ldB<PS>(Whhf, Whhh, Whhl, n0*512 + kc + k, bh0, bl0);
    ldB<PS>(Whhf, Whhh, Whhl, n1*512 + kc + k, bh1, bl1);
    SMACC(acc0, ah, al, bh0, bl0);
    SMACC(acc1, ah, al, bh1, bl1);
  }
  cell_epilogue(gl, bs, c0, hnhi, hnlo, nullptr, mrow, jblk, acc0, acc1, wv, lane, tid);
}

// ---- layer 1: gates = [h0_t | h1_{t-1}] @ [Wih1|Whh1]^T --------------------
template<bool PS>
__global__ void __launch_bounds__(256) l1_step(
    const float* __restrict__ Wihf, const u16* __restrict__ Wihh, const u16* __restrict__ Wihl,
    const float* __restrict__ Whhf, const u16* __restrict__ Whhh, const u16* __restrict__ Whhl,
    const float* __restrict__ bih, const float* __restrict__ bhh,
    const u16* __restrict__ h0hi, const u16* __restrict__ h0lo,
    const u16* __restrict__ h1phi, const u16* __restrict__ h1plo,
    u16* __restrict__ h1nhi, u16* __restrict__ h1nlo,
    float* __restrict__ c1, float* __restrict__ gfout)
{
  __shared__ float gl[64*33];
  __shared__ float bs[32];
  const int wg = blockIdx.x, tid = threadIdx.x;
  const int mrow = wg & 3, jblk = wg >> 2;
  const int lane = tid & 63, wv = tid >> 6;
  if (tid < 32){
    int n = ((tid >> 3) << 9) + jblk*8 + (tid & 7);
    bs[tid] = bih[n] + bhh[n];
  }
  const int ar = mrow*64 + wv*16 + (lane & 15);
  const int kc = (lane >> 4) << 3;
  const int cI = lane & 15;
  const int n0 = ((cI >> 3) << 9) + jblk*8 + (cI & 7);
  const int n1 = n0 + 1024;

  f32x4 acc0 = {0,0,0,0}, acc1 = {0,0,0,0};
  {
    const u16* hH = h0hi + ar*512 + kc;
    const u16* hL = h0lo + ar*512 + kc;
    #pragma unroll 4
    for (int ks = 0; ks < 16; ++ks){
      int k = ks*32;
      short8 ah = *(const short8*)(hH + k);
      short8 al = *(const short8*)(hL + k);
      short8 bh0, bl0, bh1, bl1;
      ldB<PS>(Wihf, Wihh, Wihl, n0*512 + kc + k, bh0, bl0);
      ldB<PS>(Wihf, Wihh, Wihl, n1*512 + kc + k, bh1, bl1);
      SMACC(acc0, ah, al, bh0, bl0);
      SMACC(acc1, ah, al, bh1, bl1);
    }
  }
  {
    const u16* hH = h1phi + ar*512 + kc;
    const u16* hL = h1plo + ar*512 + kc;
    #pragma unroll 4
    for (int ks = 0; ks < 16; ++ks){
      int k = ks*32;
      short8 ah = *(const short8*)(hH + k);
      short8 al = *(const short8*)(hL + k);
      short8 bh0, bl0, bh1, bl1;
      ldB<PS>(Whhf, Whhh, Whhl, n0*512 + kc + k, bh0, bl0);
      ldB<PS>(Whhf, Whhh, Whhl, n1*512 + kc + k, bh1, bl1);
      SMACC(acc0, ah, al, bh0, bl0);
      SMACC(acc1, ah, al, bh1, bl1);
    }
  }
  cell_epilogue(gl, bs, c1, h1nhi, h1nlo, gfout, mrow, jblk, acc0, acc1, wv, lane, tid);
}

// ---- decoder: pred = h1_t @ Wout^T + bout ----------------------------------
__global__ void __launch_bounds__(256) pred_step(
    const u16* __restrict__ h1hi, const u16* __restrict__ h1lo,
    const float* __restrict__ Wout, const float* __restrict__ bout,
    u16* __restrict__ predhi, u16* __restrict__ predlo,
    float* __restrict__ out, int l)
{
  const int wg = blockIdx.x, tid = threadIdx.x;
  const int bsub = tid >> 6, d = tid & 63;
  const int b = wg*4 + bsub;
  float acc = bout[d];
  const u16* hH = h1hi + b*512;
  const u16* hL = h1lo + b*512;
  const float* wr = Wout + d*512;
  #pragma unroll 8
  for (int k = 0; k < 512; k += 8){
    short8 hv = *(const short8*)(hH + k);
    short8 lv = *(const short8*)(hL + k);
    #pragma unroll
    for (int j = 0; j < 8; ++j)
      acc += (bf2f((u16)hv[j]) + bf2f((u16)lv[j])) * wr[k + j];
  }
  HiLo s = split1(acc);
  predhi[b*64 + d] = (u16)s.hi;                     // feedback (hi)
  predlo[b*64 + d] = (u16)s.lo;                     // feedback (lo)
  out[131072 + (b*64 + d)*96 + l] = acc;            // preds[b][d][l] (f32)
}

extern "C" void kernel_launch(void* const* d_in, const int* in_sizes, int n_in,
                              void* d_out, int out_size, void* d_ws, size_t ws_size,
                              hipStream_t stream)
{
  const float* x    = (const float*)d_in[0];
  const float* Wih0 = (const float*)d_in[1];
  const float* Whh0 = (const float*)d_in[2];
  const float* bih0 = (const float*)d_in[3];
  const float* bhh0 = (const float*)d_in[4];
  const float* Wih1 = (const float*)d_in[5];
  const float* Whh1 = (const float*)d_in[6];
  const float* bih1 = (const float*)d_in[7];
  const float* bhh1 = (const float*)d_in[8];
  const float* Wout = (const float*)d_in[9];
  const float* bout = (const float*)d_in[10];
  float* out = (float*)d_out;                 // f32 output

  // ---- ws layout: state (3,211,264 B) + pre-split weights (13,107,200 B)
  char* ws = (char*)d_ws;
  u16* h0h[2] = { (u16*)(ws + 0),       (u16*)(ws + 262144) };
  u16* h0l[2] = { (u16*)(ws + 524288),  (u16*)(ws + 786432) };
  u16* h1h[2] = { (u16*)(ws + 1048576), (u16*)(ws + 1310720) };
  u16* h1l[2] = { (u16*)(ws + 1572864), (u16*)(ws + 1835008) };
  float* c0   = (float*)(ws + 2097152);
  float* c1   = (float*)(ws + 2621440);
  u16* predh  = (u16*)(ws + 3145728);
  u16* predl  = (u16*)(ws + 3178496);
  char* wb = ws + 3211264;
  u16* W0ih_h = (u16*)wb;               u16* W0ih_l = W0ih_h + 131072;
  u16* W0hh_h = W0ih_l + 131072;        u16* W0hh_l = W0hh_h + 1048576;
  u16* W1ih_h = W0hh_l + 1048576;       u16* W1ih_l = W1ih_h + 1048576;
  u16* W1hh_h = W1ih_l + 1048576;       u16* W1hh_l = W1hh_h + 1048576;
  const size_t NEED = 3211264u + 13107200u;
  const bool ps = (ws_size >= NEED);    // fall back to in-register split if tight

  (void)hipMemsetAsync(d_ws, 0, 3211264, stream);   // zero h/c/pred each call

  if (ps){
    wsplit<<<dim3(131072/256),  dim3(256), 0, stream>>>(Wih0, W0ih_h, W0ih_l, 131072);
    wsplit<<<dim3(1048576/256), dim3(256), 0, stream>>>(Whh0, W0hh_h, W0hh_l, 1048576);
    wsplit<<<dim3(1048576/256), dim3(256), 0, stream>>>(Wih1, W1ih_h, W1ih_l, 1048576);
    wsplit<<<dim3(1048576/256), dim3(256), 0, stream>>>(Whh1, W1hh_h, W1hh_l, 1048576);
  }

  for (int t = 0; t < 432; ++t){
    const int p = t & 1;
    float* gf = (t == 335) ? out : (float*)nullptr;
    if (t < 336){
      if (ps) l0_step<true,true><<<dim3(256), dim3(256), 0, stream>>>(
          x, predh, predl, Wih0, W0ih_h, W0ih_l, Whh0, W0hh_h, W0hh_l,
          bih0, bhh0, h0h[p^1], h0l[p^1], h0h[p], h0l[p], c0, t);
      else    l0_step<true,false><<<dim3(256), dim3(256), 0, stream>>>(
          x, predh, predl, Wih0, W0ih_h, W0ih_l, Whh0, W0hh_h, W0hh_l,
          bih0, bhh0, h0h[p^1], h0l[p^1], h0h[p], h0l[p], c0, t);
    } else {
      if (ps) l0_step<false,true><<<dim3(256), dim3(256), 0, stream>>>(
          x, predh, predl, Wih0, W0ih_h, W0ih_l, Whh0, W0hh_h, W0hh_l,
          bih0, bhh0, h0h[p^1], h0l[p^1], h0h[p], h0l[p], c0, t);
      else    l0_step<false,false><<<dim3(256), dim3(256), 0, stream>>>(
          x, predh, predl, Wih0, W0ih_h, W0ih_l, Whh0, W0hh_h, W0hh_l,
          bih0, bhh0, h0h[p^1], h0l[p^1], h0h[p], h0l[p], c0, t);
    }
    if (ps) l1_step<true><<<dim3(256), dim3(256), 0, stream>>>(
        Wih1, W1ih_h, W1ih_l, Whh1, W1hh_h, W1hh_l, bih1, bhh1,
        h0h[p], h0l[p], h1h[p^1], h1l[p^1], h1h[p], h1l[p], c1, gf);
    else    l1_step<false><<<dim3(256), dim3(256), 0, stream>>>(
        Wih1, W1ih_h, W1ih_l, Whh1, W1hh_h, W1hh_l, bih1, bhh1,
        h0h[p], h0l[p], h1h[p^1], h1l[p^1], h1h[p], h1l[p], c1, gf);
    if (t >= 336)
      pred_step<<<dim3(64), dim3(256), 0, stream>>>(
          h1h[p], h1l[p], Wout, bout, predh, predl, out, t - 336);
  }
}